// Round 5
// baseline (1642.270 us; speedup 1.0000x reference)
//
#include <hip/hip_runtime.h>
#include <hip/hip_cooperative_groups.h>

namespace cg = cooperative_groups;

#define BATCH 4
#define T 8192
#define RES 256
#define SKIPC 512
#define NCLSC 256
#define NLAYERS 30
#define T0 5120
#define TBUF 3072
#define NT 32
#define STR 264               // LDS row stride in shorts (528 B): 2-way banks, 16B-aligned
#define TAPSZ (NT * STR)      // 8448 shorts per tap buffer
#define NBLK 256              // 1 block/CU -> cooperative launch always admissible

typedef __attribute__((ext_vector_type(8))) short short8x;   // 8 bf16
typedef __attribute__((ext_vector_type(4))) float floatx4;   // MFMA C/D
typedef unsigned short ushort_t;
typedef unsigned long long ull;

__device__ __forceinline__ ushort_t f2bf(float f) {
    unsigned u = __float_as_uint(f);
    u += 0x7fffu + ((u >> 16) & 1u);
    return (ushort_t)(u >> 16);
}
__device__ __forceinline__ float bf2f(ushort_t h) {
    return __uint_as_float(((unsigned)h) << 16);
}

// ---------------------------------------------------------------------------
// Fused cooperative kernel: prep -> start -> 30 layers -> skip -> end MLP
// ---------------------------------------------------------------------------
__global__ __launch_bounds__(512, 2) void fused_kernel(
    const float* __restrict__ x, const float* __restrict__ Wst, const float* __restrict__ bst,
    const float* __restrict__ Wd, const float* __restrict__ bd_all,
    const float* __restrict__ Wr, const float* __restrict__ br_all,
    const float* __restrict__ Ws, const float* __restrict__ bs,
    const float* __restrict__ W1, const float* __restrict__ b1,
    const float* __restrict__ W2, const float* __restrict__ b2,
    float* __restrict__ hf, ushort_t* __restrict__ hb0, ushort_t* __restrict__ hb1,
    ushort_t* __restrict__ Asw, ushort_t* __restrict__ Rsw, ushort_t* __restrict__ WsT,
    float* __restrict__ gstore, float* __restrict__ skip, float* __restrict__ e1ws,
    float* __restrict__ out)
{
    cg::grid_group grid = cg::this_grid();
    __shared__ __align__(16) ushort_t st[2 * TAPSZ];   // 33.8 KB

    const int tid = threadIdx.x;
    const int bid = blockIdx.x;
    const long gstride = (long)NBLK * 512;

    // ---------- phase P: weight prep (swizzled A-fragment order) ----------
    {
        const long R0 = 30L * 131072, R1 = 30L * 65536, R2 = 30L * 131072;
        for (long id0 = (long)bid * 512 + tid; id0 < R0 + R1 + R2; id0 += gstride) {
            long id = id0;
            if (id < R0) {
                long l = id >> 17; int r = (int)(id & 131071);
                int j = r & 7, lane = (r >> 3) & 63, f = (r >> 9) & 1, s = (r >> 10) & 15, wv = r >> 14;
                int row = wv * 32 + f * 16 + (lane & 15);
                int k = s * 32 + (lane >> 4) * 8 + j;
                int cin = k & 255, kk = k >> 8;
                Asw[id] = f2bf(Wd[((l * 256 + row) * 256 + cin) * 2 + kk]);
                continue;
            }
            id -= R0;
            if (id < R1) {
                long l = id >> 16; int r = (int)(id & 65535);
                int j = r & 7, lane = (r >> 3) & 63, f = (r >> 9) & 1, s = (r >> 10) & 7, wv = r >> 13;
                int row = wv * 32 + f * 16 + (lane & 15);
                int k = s * 32 + (lane >> 4) * 8 + j;
                Rsw[id] = f2bf(Wr[(l * 256 + row) * 256 + k]);
                continue;
            }
            id -= R1;
            int o = (int)(id & 511); long rest = id >> 9; int cin = (int)(rest & 255); long l = rest >> 8;
            WsT[id] = f2bf(Ws[(l * 512 + o) * 256 + cin]);
        }
    }
    grid.sync();

    // ---------- phase S: start conv h0[b][t][c] + zero skip ----------
    for (long id = (long)bid * 512 + tid; id < (long)BATCH * TBUF * RES; id += gstride) {
        int c = (int)(id & 255);
        int ti = (int)((id >> 8) % TBUF);
        int b  = (int)((id >> 8) / TBUF);
        int t = T0 + ti;
        float v = Wst[2 * c] * x[b * T + t - 1] + Wst[2 * c + 1] * x[b * T + t] + bst[c];
        hf[id] = v;
        hb0[id] = f2bf(v);
    }
    for (int id = bid * 512 + tid; id < BATCH * SKIPC; id += NBLK * 512) skip[id] = 0.f;
    grid.sync();

    // ---------- 30 layers ----------
    const int wv = tid >> 6, lane = tid & 63;
    const int quad = lane >> 4, l16 = lane & 15;

    for (int l = 0; l < NLAYERS; ++l) {
        const int dil = 1 << (l % 10);
        int rem_next = 0;
        for (int j = l + 1; j < NLAYERS; ++j) rem_next += 1 << (j % 10);
        const int s_out = 8191 - rem_next;
        const int ntiles = (rem_next + 32) >> 5;
        const int njobs = ntiles * BATCH;              // max 384
        const ushort_t* __restrict__ hA_all = (l & 1) ? hb1 : hb0;
        ushort_t* __restrict__ hB_all = (l & 1) ? hb0 : hb1;
        const ushort_t* __restrict__ AswL = Asw + (size_t)l * 131072;
        const ushort_t* __restrict__ RswL = Rsw + (size_t)l * 65536;
        const float* __restrict__ bdL = bd_all + l * RES;
        const float* __restrict__ brL = br_all + l * RES;
        float* __restrict__ gsL = gstore + (size_t)l * BATCH * RES;

        for (int job = bid; job < njobs; job += NBLK) {
            const int tile = job >> 2, b = job & 3;
            const int tb = 8192 - NT * (tile + 1);
            const int mb = wv * 32;

            float* __restrict__ hfb = hf + (size_t)b * TBUF * RES;
            const ushort_t* __restrict__ hA = hA_all + (size_t)b * TBUF * RES;
            ushort_t* __restrict__ hB = hB_all + (size_t)b * TBUF * RES;

            // Stage tap0 (t-dil) and tap1 (t): coalesced 16 B chunks.
            #pragma unroll
            for (int tp = 0; tp < 2; ++tp) {
                const int dsub = tp ? 0 : dil;
                #pragma unroll
                for (int p = 0; p < 2; ++p) {
                    int c = p * 512 + tid;
                    int row = c >> 5, off = (c & 31) * 8;
                    int tt = tb + row - dsub - T0;
                    tt = tt < 0 ? 0 : tt;
                    *(float4*)&st[tp * TAPSZ + row * STR + off] =
                        *(const float4*)(hA + (size_t)tt * RES + off);
                }
            }
            __syncthreads();

            floatx4 acc00, acc01, acc10, acc11;
            {
                float4 c0 = *(const float4*)(bdL + mb + quad * 4);
                float4 c1 = *(const float4*)(bdL + mb + 16 + quad * 4);
                acc00 = acc01 = (floatx4){c0.x, c0.y, c0.z, c0.w};
                acc10 = acc11 = (floatx4){c1.x, c1.y, c1.z, c1.w};
            }

            const ushort_t* aw = AswL + (size_t)wv * 16384 + lane * 8;
            const int u0 = l16 * STR + quad * 8;
            const int u1 = u0 + 16 * STR;

            // Conv GEMM: K=512 (s<8: tap0 = t-dil, s>=8: tap1 = t)
            #pragma unroll
            for (int s = 0; s < 16; ++s) {
                const int tbs = (s < 8 ? 0 : TAPSZ) + (s & 7) * 32;
                short8x a0 = *(const short8x*)(aw + s * 1024);
                short8x a1 = *(const short8x*)(aw + s * 1024 + 512);
                short8x g0 = *(const short8x*)&st[tbs + u0];
                short8x g1 = *(const short8x*)&st[tbs + u1];
                acc00 = __builtin_amdgcn_mfma_f32_16x16x32_bf16(a0, g0, acc00, 0, 0, 0);
                acc10 = __builtin_amdgcn_mfma_f32_16x16x32_bf16(a1, g0, acc10, 0, 0, 0);
                acc01 = __builtin_amdgcn_mfma_f32_16x16x32_bf16(a0, g1, acc01, 0, 0, 0);
                acc11 = __builtin_amdgcn_mfma_f32_16x16x32_bf16(a1, g1, acc11, 0, 0, 0);
            }
            __syncthreads();

            // gate -> LDS (overlay tap0); capture t=8191 col fp32
            #pragma unroll
            for (int mt = 0; mt < 2; ++mt) {
                #pragma unroll
                for (int nt = 0; nt < 2; ++nt) {
                    floatx4 a = mt == 0 ? (nt == 0 ? acc00 : acc01) : (nt == 0 ? acc10 : acc11);
                    float gf[4];
                    ull pk = 0;
                    #pragma unroll
                    for (int r = 0; r < 4; ++r) {
                        float d = a[r];
                        float sig = 1.f / (1.f + __expf(-d));
                        float th = 1.f - 2.f / (__expf(2.f * d) + 1.f);
                        gf[r] = th * sig;
                        pk |= ((ull)f2bf(gf[r])) << (16 * r);
                    }
                    const int n = nt * 16 + l16;
                    const int m = mb + mt * 16 + quad * 4;
                    *(ull*)&st[n * STR + m] = pk;
                    if (tile == 0 && n == 31) {
                        float4 g4 = {gf[0], gf[1], gf[2], gf[3]};
                        *(float4*)&gsL[b * RES + m] = g4;
                    }
                }
            }
            __syncthreads();

            // Residual GEMM: h' = h + Wr @ gated, K=256
            const ushort_t* rw = RswL + (size_t)wv * 8192 + lane * 8;
            floatx4 r00, r01, r10, r11;
            {
                float4 c0 = *(const float4*)(brL + mb + quad * 4);
                float4 c1 = *(const float4*)(brL + mb + 16 + quad * 4);
                r00 = r01 = (floatx4){c0.x, c0.y, c0.z, c0.w};
                r10 = r11 = (floatx4){c1.x, c1.y, c1.z, c1.w};
            }
            #pragma unroll
            for (int s = 0; s < 8; ++s) {
                short8x a0 = *(const short8x*)(rw + s * 1024);
                short8x a1 = *(const short8x*)(rw + s * 1024 + 512);
                short8x g0 = *(const short8x*)&st[s * 32 + u0];
                short8x g1 = *(const short8x*)&st[s * 32 + u1];
                r00 = __builtin_amdgcn_mfma_f32_16x16x32_bf16(a0, g0, r00, 0, 0, 0);
                r10 = __builtin_amdgcn_mfma_f32_16x16x32_bf16(a1, g0, r10, 0, 0, 0);
                r01 = __builtin_amdgcn_mfma_f32_16x16x32_bf16(a0, g1, r01, 0, 0, 0);
                r11 = __builtin_amdgcn_mfma_f32_16x16x32_bf16(a1, g1, r11, 0, 0, 0);
            }

            // Epilogue: in-place fp32 residual add + bf16 copy; only valid columns
            #pragma unroll
            for (int nt = 0; nt < 2; ++nt) {
                const int t = tb + nt * 16 + l16;
                if (t < s_out) continue;
                const size_t base = (size_t)(t - T0) * RES;
                #pragma unroll
                for (int mt = 0; mt < 2; ++mt) {
                    const int m = mb + mt * 16 + quad * 4;
                    floatx4 ad = mt == 0 ? (nt == 0 ? r00 : r01) : (nt == 0 ? r10 : r11);
                    float4 ho = *(const float4*)(hfb + base + m);
                    float4 hn = {ho.x + ad[0], ho.y + ad[1], ho.z + ad[2], ho.w + ad[3]};
                    *(float4*)(hfb + base + m) = hn;
                    ull pk = (ull)f2bf(hn.x) | ((ull)f2bf(hn.y) << 16)
                           | ((ull)f2bf(hn.z) << 32) | ((ull)f2bf(hn.w) << 48);
                    *(ull*)(hB + base + m) = pk;
                }
            }
            __syncthreads();
        }
        grid.sync();
    }

    // ---------- skip matvecs: 120 blocks = (l, b) ----------
    if (bid < NLAYERS * BATCH) {
        const int l = bid >> 2, b = bid & 3, o = tid;
        const ushort_t* w = WsT + (size_t)l * 131072;
        const float* g = gstore + (size_t)(l * BATCH + b) * RES;
        float a = bs[l * SKIPC + o];
        #pragma unroll 4
        for (int cin = 0; cin < RES; ++cin)
            a = fmaf(bf2f(w[cin * SKIPC + o]), g[cin], a);
        atomicAdd(&skip[b * SKIPC + o], a);
    }
    grid.sync();

    // ---------- end1: e1 = relu(W1 @ relu(skip) + b1); 64 blocks ----------
    float* sf = (float*)st;
    float* part = sf + SKIPC;
    if (bid < 64) {
        const int b = bid >> 4, og = bid & 15;
        sf[tid] = fmaxf(skip[b * SKIPC + tid], 0.f);
        __syncthreads();
        const int o_l = tid >> 4, kp = tid & 15;
        const float* w = W1 + (size_t)(og * 32 + o_l) * SKIPC + kp * 32;
        const float* sp = sf + kp * 32;
        float a = 0.f;
        #pragma unroll 8
        for (int j = 0; j < 32; ++j) a = fmaf(w[j], sp[j], a);
        part[tid] = a;
        __syncthreads();
        if (tid < 32) {
            float r = b1[og * 32 + tid];
            #pragma unroll
            for (int k = 0; k < 16; ++k) r += part[tid * 16 + k];
            e1ws[b * SKIPC + og * 32 + tid] = fmaxf(r, 0.f);
        }
    }
    grid.sync();

    // ---------- end2: out = W2 @ e1 + b2; 32 blocks ----------
    if (bid < 32) {
        const int b = bid >> 3, og = bid & 7;
        sf[tid] = e1ws[b * SKIPC + tid];
        __syncthreads();
        const int o_l = tid >> 4, kp = tid & 15;
        const float* w = W2 + (size_t)(og * 32 + o_l) * SKIPC + kp * 32;
        const float* ep = sf + kp * 32;
        float a = 0.f;
        #pragma unroll 8
        for (int j = 0; j < 32; ++j) a = fmaf(w[j], ep[j], a);
        part[tid] = a;
        __syncthreads();
        if (tid < 32) {
            float r = b2[og * 32 + tid];
            #pragma unroll
            for (int k = 0; k < 16; ++k) r += part[tid * 16 + k];
            out[b * NCLSC + og * 32 + tid] = r;
        }
    }
}

// ---------------------------------------------------------------------------
// Fallback path (round-3 multi-kernel, known-good) — used only if the
// cooperative launch is rejected at runtime.
// ---------------------------------------------------------------------------
__global__ __launch_bounds__(256) void prep_kernel(
    const float* __restrict__ Wd, const float* __restrict__ Wr,
    const float* __restrict__ Ws,
    ushort_t* __restrict__ Aswz, ushort_t* __restrict__ Rswz,
    ushort_t* __restrict__ WsT)
{
    long id = (long)blockIdx.x * 256 + threadIdx.x;
    const long R0 = 30L * 131072, R1 = 30L * 65536, R2 = 30L * 131072;
    if (id < R0) {
        long l = id >> 17; int r = (int)(id & 131071);
        int j = r & 7, lane = (r >> 3) & 63, f = (r >> 9) & 1, s = (r >> 10) & 15, wv = r >> 14;
        int row = wv * 32 + f * 16 + (lane & 15);
        int k = s * 32 + (lane >> 4) * 8 + j;
        int cin = k & 255, kk = k >> 8;
        Aswz[id] = f2bf(Wd[((l * 256 + row) * 256 + cin) * 2 + kk]);
        return;
    }
    id -= R0;
    if (id < R1) {
        long l = id >> 16; int r = (int)(id & 65535);
        int j = r & 7, lane = (r >> 3) & 63, f = (r >> 9) & 1, s = (r >> 10) & 7, wv = r >> 13;
        int row = wv * 32 + f * 16 + (lane & 15);
        int k = s * 32 + (lane >> 4) * 8 + j;
        Rswz[id] = f2bf(Wr[(l * 256 + row) * 256 + k]);
        return;
    }
    id -= R1;
    if (id < R2) {
        int o = (int)(id & 511); long rest = id >> 9; int cin = (int)(rest & 255); long l = rest >> 8;
        WsT[id] = f2bf(Ws[(l * 512 + o) * 256 + cin]);
    }
}

__global__ __launch_bounds__(256) void start_kernel(
    const float* __restrict__ x, const float* __restrict__ Wst,
    const float* __restrict__ bst, float* __restrict__ hf, ushort_t* __restrict__ hb)
{
    int id = blockIdx.x * 256 + threadIdx.x;
    int c = id & 255;
    int ti = (id >> 8) % TBUF;
    int b  = (id >> 8) / TBUF;
    int t = T0 + ti;
    float v = Wst[2 * c] * x[b * T + t - 1] + Wst[2 * c + 1] * x[b * T + t] + bst[c];
    hf[id] = v;
    hb[id] = f2bf(v);
}

__global__ __launch_bounds__(512) void layer_kernel(
    float* __restrict__ hf,
    const ushort_t* __restrict__ hbA,
    ushort_t* __restrict__ hbB,
    const ushort_t* __restrict__ Aswz,
    const float* __restrict__ bd,
    const ushort_t* __restrict__ Rswz,
    const float* __restrict__ br,
    float* __restrict__ gstoreL,
    int dil, int s_out)
{
    __shared__ __align__(16) ushort_t st[2 * TAPSZ];

    const int tid = threadIdx.x;
    const int wv = tid >> 6, lane = tid & 63;
    const int quad = lane >> 4, l16 = lane & 15;
    const int tile = blockIdx.x, b = blockIdx.y;
    const int tb = 8192 - NT * (tile + 1);
    const int mb = wv * 32;

    float* __restrict__ hfb = hf + (size_t)b * TBUF * RES;
    const ushort_t* __restrict__ hA = hbA + (size_t)b * TBUF * RES;
    ushort_t* __restrict__ hB = hbB + (size_t)b * TBUF * RES;

    #pragma unroll
    for (int tp = 0; tp < 2; ++tp) {
        const int dsub = tp ? 0 : dil;
        #pragma unroll
        for (int p = 0; p < 2; ++p) {
            int c = p * 512 + tid;
            int row = c >> 5, off = (c & 31) * 8;
            int tt = tb + row - dsub - T0;
            tt = tt < 0 ? 0 : tt;
            *(float4*)&st[tp * TAPSZ + row * STR + off] =
                *(const float4*)(hA + (size_t)tt * RES + off);
        }
    }
    __syncthreads();

    floatx4 acc00, acc01, acc10, acc11;
    {
        float4 c0 = *(const float4*)(bd + mb + quad * 4);
        float4 c1 = *(const float4*)(bd + mb + 16 + quad * 4);
        acc00 = acc01 = (floatx4){c0.x, c0.y, c0.z, c0.w};
        acc10 = acc11 = (floatx4){c1.x, c1.y, c1.z, c1.w};
    }

    const ushort_t* aw = Aswz + (size_t)wv * 16384 + lane * 8;
    const int u0 = l16 * STR + quad * 8;
    const int u1 = u0 + 16 * STR;

    #pragma unroll
    for (int s = 0; s < 16; ++s) {
        const int tbs = (s < 8 ? 0 : TAPSZ) + (s & 7) * 32;
        short8x a0 = *(const short8x*)(aw + s * 1024);
        short8x a1 = *(const short8x*)(aw + s * 1024 + 512);
        short8x g0 = *(const short8x*)&st[tbs + u0];
        short8x g1 = *(const short8x*)&st[tbs + u1];
        acc00 = __builtin_amdgcn_mfma_f32_16x16x32_bf16(a0, g0, acc00, 0, 0, 0);
        acc10 = __builtin_amdgcn_mfma_f32_16x16x32_bf16(a1, g0, acc10, 0, 0, 0);
        acc01 = __builtin_amdgcn_mfma_f32_16x16x32_bf16(a0, g1, acc01, 0, 0, 0);
        acc11 = __builtin_amdgcn_mfma_f32_16x16x32_bf16(a1, g1, acc11, 0, 0, 0);
    }
    __syncthreads();

    #pragma unroll
    for (int mt = 0; mt < 2; ++mt) {
        #pragma unroll
        for (int nt = 0; nt < 2; ++nt) {
            floatx4 a = mt == 0 ? (nt == 0 ? acc00 : acc01) : (nt == 0 ? acc10 : acc11);
            float gf[4];
            ull pk = 0;
            #pragma unroll
            for (int r = 0; r < 4; ++r) {
                float d = a[r];
                float sig = 1.f / (1.f + __expf(-d));
                float th = 1.f - 2.f / (__expf(2.f * d) + 1.f);
                gf[r] = th * sig;
                pk |= ((ull)f2bf(gf[r])) << (16 * r);
            }
            const int n = nt * 16 + l16;
            const int m = mb + mt * 16 + quad * 4;
            *(ull*)&st[n * STR + m] = pk;
            if (tile == 0 && n == 31) {
                float4 g4 = {gf[0], gf[1], gf[2], gf[3]};
                *(float4*)&gstoreL[b * RES + m] = g4;
            }
        }
    }
    __syncthreads();

    const ushort_t* rw = Rswz + (size_t)wv * 8192 + lane * 8;
    floatx4 r00, r01, r10, r11;
    {
        float4 c0 = *(const float4*)(br + mb + quad * 4);
        float4 c1 = *(const float4*)(br + mb + 16 + quad * 4);
        r00 = r01 = (floatx4){c0.x, c0.y, c0.z, c0.w};
        r10 = r11 = (floatx4){c1.x, c1.y, c1.z, c1.w};
    }
    #pragma unroll
    for (int s = 0; s < 8; ++s) {
        short8x a0 = *(const short8x*)(rw + s * 1024);
        short8x a1 = *(const short8x*)(rw + s * 1024 + 512);
        short8x g0 = *(const short8x*)&st[s * 32 + u0];
        short8x g1 = *(const short8x*)&st[s * 32 + u1];
        r00 = __builtin_amdgcn_mfma_f32_16x16x32_bf16(a0, g0, r00, 0, 0, 0);
        r10 = __builtin_amdgcn_mfma_f32_16x16x32_bf16(a1, g0, r10, 0, 0, 0);
        r01 = __builtin_amdgcn_mfma_f32_16x16x32_bf16(a0, g1, r01, 0, 0, 0);
        r11 = __builtin_amdgcn_mfma_f32_16x16x32_bf16(a1, g1, r11, 0, 0, 0);
    }

    #pragma unroll
    for (int nt = 0; nt < 2; ++nt) {
        const int t = tb + nt * 16 + l16;
        if (t < s_out) continue;
        const size_t base = (size_t)(t - T0) * RES;
        #pragma unroll
        for (int mt = 0; mt < 2; ++mt) {
            const int m = mb + mt * 16 + quad * 4;
            floatx4 ad = mt == 0 ? (nt == 0 ? r00 : r01) : (nt == 0 ? r10 : r11);
            float4 ho = *(const float4*)(hfb + base + m);
            float4 hn = {ho.x + ad[0], ho.y + ad[1], ho.z + ad[2], ho.w + ad[3]};
            *(float4*)(hfb + base + m) = hn;
            ull pk = (ull)f2bf(hn.x) | ((ull)f2bf(hn.y) << 16)
                   | ((ull)f2bf(hn.z) << 32) | ((ull)f2bf(hn.w) << 48);
            *(ull*)(hB + base + m) = pk;
        }
    }
}

__global__ __launch_bounds__(512) void skip_kernel(
    const ushort_t* __restrict__ WsT, const float* __restrict__ bs,
    const float* __restrict__ gstore, float* __restrict__ skip)
{
    const int l = blockIdx.x, b = blockIdx.y, o = threadIdx.x;
    const ushort_t* w = WsT + (size_t)l * 131072;
    const float* g = gstore + (size_t)(l * BATCH + b) * RES;
    float a = bs[l * SKIPC + o];
    #pragma unroll 4
    for (int cin = 0; cin < RES; ++cin)
        a = fmaf(bf2f(w[cin * SKIPC + o]), g[cin], a);
    atomicAdd(&skip[b * SKIPC + o], a);
}

__global__ __launch_bounds__(256) void end1_kernel(
    const float* __restrict__ skip, const float* __restrict__ W1,
    const float* __restrict__ b1, float* __restrict__ e1ws)
{
    __shared__ float s[SKIPC];
    __shared__ float part[256];
    const int b = blockIdx.x, og = blockIdx.y, tid = threadIdx.x;
    s[tid]       = fmaxf(skip[b * SKIPC + tid], 0.f);
    s[tid + 256] = fmaxf(skip[b * SKIPC + tid + 256], 0.f);
    __syncthreads();
    const int o_l = tid >> 3, kp = tid & 7;
    const int o = og * 32 + o_l;
    const float* w = W1 + (size_t)o * SKIPC + kp * 64;
    const float* sp = s + kp * 64;
    float a = 0.f;
    #pragma unroll 8
    for (int j = 0; j < 64; ++j) a = fmaf(w[j], sp[j], a);
    part[tid] = a;
    __syncthreads();
    if (tid < 32) {
        float r = b1[og * 32 + tid];
        #pragma unroll
        for (int k = 0; k < 8; ++k) r += part[tid * 8 + k];
        e1ws[b * SKIPC + og * 32 + tid] = fmaxf(r, 0.f);
    }
}

__global__ __launch_bounds__(256) void end2_kernel(
    const float* __restrict__ e1ws, const float* __restrict__ W2,
    const float* __restrict__ b2, float* __restrict__ out)
{
    __shared__ float e[SKIPC];
    __shared__ float part[256];
    const int b = blockIdx.x, og = blockIdx.y, tid = threadIdx.x;
    e[tid]       = e1ws[b * SKIPC + tid];
    e[tid + 256] = e1ws[b * SKIPC + tid + 256];
    __syncthreads();
    const int o_l = tid >> 3, kp = tid & 7;
    const int cls = og * 32 + o_l;
    const float* w = W2 + (size_t)cls * SKIPC + kp * 64;
    const float* ep = e + kp * 64;
    float a = 0.f;
    #pragma unroll 8
    for (int j = 0; j < 64; ++j) a = fmaf(w[j], ep[j], a);
    part[tid] = a;
    __syncthreads();
    if (tid < 32) {
        float r = b2[og * 32 + tid];
        #pragma unroll
        for (int k = 0; k < 8; ++k) r += part[tid * 8 + k];
        out[b * NCLSC + og * 32 + tid] = r;
    }
}

extern "C" void kernel_launch(void* const* d_in, const int* in_sizes, int n_in,
                              void* d_out, int out_size, void* d_ws, size_t ws_size,
                              hipStream_t stream)
{
    const float* x   = (const float*)d_in[0];
    const float* Wst = (const float*)d_in[1];
    const float* bst = (const float*)d_in[2];
    const float* Wd  = (const float*)d_in[3];
    const float* bd  = (const float*)d_in[4];
    const float* Wr  = (const float*)d_in[5];
    const float* br  = (const float*)d_in[6];
    const float* Ws  = (const float*)d_in[7];
    const float* bs  = (const float*)d_in[8];
    const float* W1  = (const float*)d_in[9];
    const float* b1  = (const float*)d_in[10];
    const float* W2  = (const float*)d_in[11];
    const float* b2  = (const float*)d_in[12];
    float* out = (float*)d_out;

    char* w = (char*)d_ws;
    float* hf     = (float*)w;     w += (size_t)BATCH * TBUF * RES * 4;
    ushort_t* hb0 = (ushort_t*)w;  w += (size_t)BATCH * TBUF * RES * 2;
    ushort_t* hb1 = (ushort_t*)w;  w += (size_t)BATCH * TBUF * RES * 2;
    ushort_t* Asw = (ushort_t*)w;  w += (size_t)NLAYERS * RES * 512 * 2;
    ushort_t* Rsw = (ushort_t*)w;  w += (size_t)NLAYERS * RES * RES * 2;
    ushort_t* WsT = (ushort_t*)w;  w += (size_t)NLAYERS * RES * SKIPC * 2;
    float* gstore = (float*)w;     w += (size_t)NLAYERS * BATCH * RES * 4;
    float* skip   = (float*)w;     w += (size_t)BATCH * SKIPC * 4;
    float* e1ws   = (float*)w;     w += (size_t)BATCH * SKIPC * 4;

    void* args[] = {
        (void*)&x, (void*)&Wst, (void*)&bst, (void*)&Wd, (void*)&bd,
        (void*)&Wr, (void*)&br, (void*)&Ws, (void*)&bs, (void*)&W1, (void*)&b1,
        (void*)&W2, (void*)&b2,
        (void*)&hf, (void*)&hb0, (void*)&hb1, (void*)&Asw, (void*)&Rsw, (void*)&WsT,
        (void*)&gstore, (void*)&skip, (void*)&e1ws, (void*)&out
    };
    hipError_t err = hipLaunchCooperativeKernel(fused_kernel, dim3(NBLK), dim3(512),
                                                args, 0, stream);
    if (err == hipSuccess) return;

    // Fallback: known-good multi-kernel path (same buffers, same math).
    prep_kernel<<<38400, 256, 0, stream>>>(Wd, Wr, Ws, Asw, Rsw, WsT);
    start_kernel<<<(BATCH * TBUF * RES) / 256, 256, 0, stream>>>(x, Wst, bst, hf, hb0);
    hipMemsetAsync(skip, 0, BATCH * SKIPC * 4, stream);

    int rem[NLAYERS + 1];
    rem[NLAYERS] = 0;
    for (int i = NLAYERS - 1; i >= 0; --i) rem[i] = rem[i + 1] + (1 << (i % 10));

    for (int i = 0; i < NLAYERS; ++i) {
        int dil = 1 << (i % 10);
        int s_out = 8191 - rem[i + 1];
        int L = 8192 - s_out;
        int ntiles = (L + NT - 1) / NT;
        const ushort_t* hin = (i & 1) ? hb1 : hb0;
        ushort_t* hout = (i & 1) ? hb0 : hb1;
        layer_kernel<<<dim3(ntiles, BATCH), 512, 0, stream>>>(
            hf, hin, hout,
            Asw + (size_t)i * RES * 512, bd + (size_t)i * RES,
            Rsw + (size_t)i * RES * RES, br + (size_t)i * RES,
            gstore + (size_t)i * BATCH * RES, dil, s_out);
    }
    skip_kernel<<<dim3(NLAYERS, BATCH), 512, 0, stream>>>(WsT, bs, gstore, skip);
    end1_kernel<<<dim3(BATCH, 16), 256, 0, stream>>>(skip, W1, b1, e1ws);
    end2_kernel<<<dim3(BATCH, 8), 256, 0, stream>>>(e1ws, W2, b2, out);
}

// Round 6
// 636.160 us; speedup vs baseline: 2.5815x; 2.5815x over previous
//
#include <hip/hip_runtime.h>

#define BATCH 4
#define T 8192
#define RES 256
#define SKIPC 512
#define NCLSC 256
#define NLAYERS 30
#define T0 5120
#define TBUF 3072
#define STR 264               // LDS row stride in shorts (528 B): even-floor banks, 16B rows

typedef __attribute__((ext_vector_type(8))) short short8x;   // 8 bf16
typedef __attribute__((ext_vector_type(4))) float floatx4;   // MFMA C/D
typedef unsigned short ushort_t;
typedef unsigned long long ull;

__device__ __forceinline__ ushort_t f2bf(float f) {
    unsigned u = __float_as_uint(f);
    u += 0x7fffu + ((u >> 16) & 1u);
    return (ushort_t)(u >> 16);
}
__device__ __forceinline__ float bf2f(ushort_t h) {
    return __uint_as_float(((unsigned)h) << 16);
}
// tanh(d)*sigmoid(d) == (1-e^-d)/(1+e^-2d); 1 exp + 1 rcp (vs 2 exp + 2 div).
// clamp d >= -80 so u=e^-d stays finite; u^2=inf is fine (finite/inf -> -0).
__device__ __forceinline__ float gatefn(float d) {
    float u = __expf(-fmaxf(d, -80.f));
    return (1.f - u) * __builtin_amdgcn_rcpf(fmaf(u, u, 1.f));
}

// ---------------------------------------------------------------------------
// prep: fully-coalesced weight swizzle.
// Asw[l] layout: byte = wv*32768 + s*2048 + f*1024 + lane*16  (kernel A-frag order)
// Rsw[l] layout: byte = wv*16384 + s*2048 + f*1024 + lane*16
// WsT[l][cin][o] via LDS tile transpose.
// ---------------------------------------------------------------------------
__global__ __launch_bounds__(256) void prep_kernel(
    const float* __restrict__ Wd, const float* __restrict__ Wr,
    const float* __restrict__ Ws,
    ushort_t* __restrict__ Asw, ushort_t* __restrict__ Rsw,
    ushort_t* __restrict__ WsT)
{
    __shared__ ushort_t lt[64][72];
    const int bid = blockIdx.x, tid = threadIdx.x;
    const int wv = tid >> 6, lane = tid & 63;

    if (bid < 960) {              // Wd: wave = 2 rows; lane reads 64B contiguous
        const int task = bid * 4 + wv;              // 0..3839 = l*128 + p
        const int l = task >> 7, p = task & 127;
        const int half = lane >> 5, c = lane & 31;
        const int row = p * 2 + half;
        const float* src = Wd + ((size_t)(l * 256 + row)) * 512 + c * 16;
        float4 v0 = *(const float4*)(src);
        float4 v1 = *(const float4*)(src + 4);
        float4 v2 = *(const float4*)(src + 8);
        float4 v3 = *(const float4*)(src + 12);
        short8x p0, p1;
        p0[0]=(short)f2bf(v0.x); p0[1]=(short)f2bf(v0.z); p0[2]=(short)f2bf(v1.x); p0[3]=(short)f2bf(v1.z);
        p0[4]=(short)f2bf(v2.x); p0[5]=(short)f2bf(v2.z); p0[6]=(short)f2bf(v3.x); p0[7]=(short)f2bf(v3.z);
        p1[0]=(short)f2bf(v0.y); p1[1]=(short)f2bf(v0.w); p1[2]=(short)f2bf(v1.y); p1[3]=(short)f2bf(v1.w);
        p1[4]=(short)f2bf(v2.y); p1[5]=(short)f2bf(v2.w); p1[6]=(short)f2bf(v3.y); p1[7]=(short)f2bf(v3.w);
        const int wr = row >> 5, f = (row >> 4) & 1, l16 = row & 15;
        const int s0 = c >> 2, q = c & 3;
        size_t base = (size_t)l * 131072
                    + (size_t)(((wr * 16 + s0) * 2 + f) * 64 + q * 16 + l16) * 8;
        *(short8x*)(Asw + base) = p0;               // kk=0 (tap t-dil), s in [0,8)
        *(short8x*)(Asw + base + 8192) = p1;        // kk=1 (tap t),    s in [8,16)
        return;
    }
    if (bid < 1920) {             // Wr
        const int task = (bid - 960) * 4 + wv;
        const int l = task >> 7, p = task & 127;
        const int half = lane >> 5, c = lane & 31;
        const int row = p * 2 + half;
        const float* src = Wr + ((size_t)(l * 256 + row)) * 256 + c * 8;
        float4 v0 = *(const float4*)(src);
        float4 v1 = *(const float4*)(src + 4);
        short8x pk;
        pk[0]=(short)f2bf(v0.x); pk[1]=(short)f2bf(v0.y); pk[2]=(short)f2bf(v0.z); pk[3]=(short)f2bf(v0.w);
        pk[4]=(short)f2bf(v1.x); pk[5]=(short)f2bf(v1.y); pk[6]=(short)f2bf(v1.z); pk[7]=(short)f2bf(v1.w);
        const int wr = row >> 5, f = (row >> 4) & 1, l16 = row & 15;
        const int s = c >> 2, q = c & 3;
        size_t base = (size_t)l * 65536
                    + (size_t)(((wr * 8 + s) * 2 + f) * 64 + q * 16 + l16) * 8;
        *(short8x*)(Rsw + base) = pk;
        return;
    }
    {                             // Ws transpose via LDS 64x64 tile
        const int t = bid - 1920;                   // 0..959 = l*32 + ot*4 + ct
        const int l = t >> 5, r = t & 31, ot = r >> 2, ct = r & 3;
        #pragma unroll 4
        for (int it = 0; it < 16; ++it) {
            int o_l = it * 4 + (tid >> 6), cin_l = tid & 63;
            lt[cin_l][o_l] = f2bf(Ws[((size_t)(l * 512 + ot * 64 + o_l)) * 256 + ct * 64 + cin_l]);
        }
        __syncthreads();
        #pragma unroll 4
        for (int it = 0; it < 16; ++it) {
            int cin_l = it * 4 + (tid >> 6), o_l = tid & 63;
            WsT[(size_t)l * 131072 + (size_t)(ct * 64 + cin_l) * 512 + ot * 64 + o_l] = lt[cin_l][o_l];
        }
    }
}

// h0[b][t][c] for t in [5120, 8191], fp32 + bf16 copies.
__global__ __launch_bounds__(256) void start_kernel(
    const float* __restrict__ x, const float* __restrict__ Wst,
    const float* __restrict__ bst, float* __restrict__ hf, ushort_t* __restrict__ hb)
{
    int id = blockIdx.x * 256 + threadIdx.x;
    int c = id & 255;
    int ti = (id >> 8) % TBUF;
    int b  = (id >> 8) / TBUF;
    int t = T0 + ti;
    float v = Wst[2 * c] * x[b * T + t - 1] + Wst[2 * c + 1] * x[b * T + t] + bst[c];
    hf[id] = v;
    hb[id] = f2bf(v);
}

// ---------------------------------------------------------------------------
// NT=32 layer (dil >= 64): two disjoint 32-col tap buffers (R3 structure).
// ---------------------------------------------------------------------------
__global__ __launch_bounds__(512) void layer32_kernel(
    float* __restrict__ hf, const ushort_t* __restrict__ hbA, ushort_t* __restrict__ hbB,
    const ushort_t* __restrict__ Aswz, const float* __restrict__ bd,
    const ushort_t* __restrict__ Rswz, const float* __restrict__ br,
    float* __restrict__ gstoreL, int dil, int s_out)
{
    __shared__ __align__(16) ushort_t st[2 * 32 * STR];   // 33.8 KB

    const int tid = threadIdx.x;
    const int wv = tid >> 6, lane = tid & 63;
    const int quad = lane >> 4, l16 = lane & 15;
    const int tile = blockIdx.x, b = blockIdx.y;
    const int tb = 8192 - 32 * (tile + 1);
    const int mb = wv * 32;

    float* __restrict__ hfb = hf + (size_t)b * TBUF * RES;
    const ushort_t* __restrict__ hA = hbA + (size_t)b * TBUF * RES;
    ushort_t* __restrict__ hB = hbB + (size_t)b * TBUF * RES;

    #pragma unroll
    for (int tp = 0; tp < 2; ++tp) {
        const int dsub = tp ? 0 : dil;
        #pragma unroll
        for (int p = 0; p < 2; ++p) {
            int c = p * 512 + tid;
            int row = c >> 5, off = (c & 31) * 8;
            int tt = tb + row - dsub - T0;
            tt = tt < 0 ? 0 : tt;
            *(float4*)&st[tp * 32 * STR + row * STR + off] =
                *(const float4*)(hA + (size_t)tt * RES + off);
        }
    }
    __syncthreads();

    floatx4 acc00, acc01, acc10, acc11;
    {
        float4 c0 = *(const float4*)(bd + mb + quad * 4);
        float4 c1 = *(const float4*)(bd + mb + 16 + quad * 4);
        acc00 = acc01 = (floatx4){c0.x, c0.y, c0.z, c0.w};
        acc10 = acc11 = (floatx4){c1.x, c1.y, c1.z, c1.w};
    }

    const ushort_t* aw = Aswz + (size_t)wv * 16384 + lane * 8;
    const int u0 = l16 * STR + quad * 8;
    const int u1 = u0 + 16 * STR;

    #pragma unroll
    for (int s = 0; s < 16; ++s) {
        const int tbs = (s < 8 ? 0 : 32 * STR) + (s & 7) * 32;
        short8x a0 = *(const short8x*)(aw + s * 1024);
        short8x a1 = *(const short8x*)(aw + s * 1024 + 512);
        short8x g0 = *(const short8x*)&st[tbs + u0];
        short8x g1 = *(const short8x*)&st[tbs + u1];
        acc00 = __builtin_amdgcn_mfma_f32_16x16x32_bf16(a0, g0, acc00, 0, 0, 0);
        acc10 = __builtin_amdgcn_mfma_f32_16x16x32_bf16(a1, g0, acc10, 0, 0, 0);
        acc01 = __builtin_amdgcn_mfma_f32_16x16x32_bf16(a0, g1, acc01, 0, 0, 0);
        acc11 = __builtin_amdgcn_mfma_f32_16x16x32_bf16(a1, g1, acc11, 0, 0, 0);
    }
    __syncthreads();

    #pragma unroll
    for (int mt = 0; mt < 2; ++mt) {
        #pragma unroll
        for (int nt = 0; nt < 2; ++nt) {
            floatx4 a = mt == 0 ? (nt == 0 ? acc00 : acc01) : (nt == 0 ? acc10 : acc11);
            float gf[4];
            ull pk = 0;
            #pragma unroll
            for (int r = 0; r < 4; ++r) {
                gf[r] = gatefn(a[r]);
                pk |= ((ull)f2bf(gf[r])) << (16 * r);
            }
            const int n = nt * 16 + l16;
            const int m = mb + mt * 16 + quad * 4;
            *(ull*)&st[n * STR + m] = pk;
            if (tile == 0 && n == 31) {
                float4 g4 = {gf[0], gf[1], gf[2], gf[3]};
                *(float4*)&gstoreL[b * RES + m] = g4;
            }
        }
    }
    __syncthreads();

    const ushort_t* rw = Rswz + (size_t)wv * 8192 + lane * 8;
    floatx4 r00, r01, r10, r11;
    {
        float4 c0 = *(const float4*)(br + mb + quad * 4);
        float4 c1 = *(const float4*)(br + mb + 16 + quad * 4);
        r00 = r01 = (floatx4){c0.x, c0.y, c0.z, c0.w};
        r10 = r11 = (floatx4){c1.x, c1.y, c1.z, c1.w};
    }
    #pragma unroll
    for (int s = 0; s < 8; ++s) {
        short8x a0 = *(const short8x*)(rw + s * 1024);
        short8x a1 = *(const short8x*)(rw + s * 1024 + 512);
        short8x g0 = *(const short8x*)&st[s * 32 + u0];
        short8x g1 = *(const short8x*)&st[s * 32 + u1];
        r00 = __builtin_amdgcn_mfma_f32_16x16x32_bf16(a0, g0, r00, 0, 0, 0);
        r10 = __builtin_amdgcn_mfma_f32_16x16x32_bf16(a1, g0, r10, 0, 0, 0);
        r01 = __builtin_amdgcn_mfma_f32_16x16x32_bf16(a0, g1, r01, 0, 0, 0);
        r11 = __builtin_amdgcn_mfma_f32_16x16x32_bf16(a1, g1, r11, 0, 0, 0);
    }

    #pragma unroll
    for (int nt = 0; nt < 2; ++nt) {
        const int t = tb + nt * 16 + l16;
        if (t < s_out) continue;
        const size_t base = (size_t)(t - T0) * RES;
        #pragma unroll
        for (int mt = 0; mt < 2; ++mt) {
            const int m = mb + mt * 16 + quad * 4;
            floatx4 ad = mt == 0 ? (nt == 0 ? r00 : r01) : (nt == 0 ? r10 : r11);
            float4 ho = *(const float4*)(hfb + base + m);
            float4 hn = {ho.x + ad[0], ho.y + ad[1], ho.z + ad[2], ho.w + ad[3]};
            *(float4*)(hfb + base + m) = hn;
            ull pk = (ull)f2bf(hn.x) | ((ull)f2bf(hn.y) << 16)
                   | ((ull)f2bf(hn.z) << 32) | ((ull)f2bf(hn.w) << 48);
            *(ull*)(hB + base + m) = pk;
        }
    }
}

// ---------------------------------------------------------------------------
// NT=64 layer (dil <= 32): single union tap range [tb-dil, tb+64), <= 96 rows.
// Halves per-column weight traffic and job count vs NT=32.
// ---------------------------------------------------------------------------
__global__ __launch_bounds__(512, 2) void layer64_kernel(
    float* __restrict__ hf, const ushort_t* __restrict__ hbA, ushort_t* __restrict__ hbB,
    const ushort_t* __restrict__ Aswz, const float* __restrict__ bd,
    const ushort_t* __restrict__ Rswz, const float* __restrict__ br,
    float* __restrict__ gstoreL, int dil, int s_out)
{
    __shared__ __align__(16) ushort_t st[96 * STR];       // 50.7 KB

    const int tid = threadIdx.x;
    const int wv = tid >> 6, lane = tid & 63;
    const int quad = lane >> 4, l16 = lane & 15;
    const int tile = blockIdx.x, b = blockIdx.y;
    const int tb = 8192 - 64 * (tile + 1);
    const int mb = wv * 32;
    const int nrows = 64 + dil;

    float* __restrict__ hfb = hf + (size_t)b * TBUF * RES;
    const ushort_t* __restrict__ hA = hbA + (size_t)b * TBUF * RES;
    ushort_t* __restrict__ hB = hbB + (size_t)b * TBUF * RES;

    // stage union range; row r <-> t = tb - dil + r
    for (int it = 0; it < 6; ++it) {
        int idx = it * 512 + tid;
        if (idx < nrows * 32) {
            int row = idx >> 5, off = (idx & 31) * 8;
            int tt = tb - dil + row - T0;
            tt = tt < 0 ? 0 : tt;
            *(float4*)&st[row * STR + off] = *(const float4*)(hA + (size_t)tt * RES + off);
        }
    }
    __syncthreads();

    floatx4 acc[2][4];
    {
        float4 c0 = *(const float4*)(bd + mb + quad * 4);
        float4 c1 = *(const float4*)(bd + mb + 16 + quad * 4);
        #pragma unroll
        for (int nt = 0; nt < 4; ++nt) {
            acc[0][nt] = (floatx4){c0.x, c0.y, c0.z, c0.w};
            acc[1][nt] = (floatx4){c1.x, c1.y, c1.z, c1.w};
        }
    }

    const ushort_t* aw = Aswz + (size_t)wv * 16384 + lane * 8;
    #pragma unroll
    for (int s = 0; s < 16; ++s) {
        short8x a0 = *(const short8x*)(aw + s * 1024);
        short8x a1 = *(const short8x*)(aw + s * 1024 + 512);
        const int roff = (s < 8) ? 0 : dil;               // s<8: tap t-dil (row=col)
        const int cb = (roff + l16) * STR + (s & 7) * 32 + quad * 8;
        #pragma unroll
        for (int nt = 0; nt < 4; ++nt) {
            short8x bb = *(const short8x*)&st[cb + nt * 16 * STR];
            acc[0][nt] = __builtin_amdgcn_mfma_f32_16x16x32_bf16(a0, bb, acc[0][nt], 0, 0, 0);
            acc[1][nt] = __builtin_amdgcn_mfma_f32_16x16x32_bf16(a1, bb, acc[1][nt], 0, 0, 0);
        }
    }
    __syncthreads();

    // gate -> LDS overlay rows 0..63
    #pragma unroll
    for (int mt = 0; mt < 2; ++mt) {
        #pragma unroll
        for (int nt = 0; nt < 4; ++nt) {
            floatx4 a = acc[mt][nt];
            float gf[4];
            ull pk = 0;
            #pragma unroll
            for (int r = 0; r < 4; ++r) {
                gf[r] = gatefn(a[r]);
                pk |= ((ull)f2bf(gf[r])) << (16 * r);
            }
            const int n = nt * 16 + l16;
            const int m = mb + mt * 16 + quad * 4;
            *(ull*)&st[n * STR + m] = pk;
            if (tile == 0 && n == 63) {
                float4 g4 = {gf[0], gf[1], gf[2], gf[3]};
                *(float4*)&gstoreL[b * RES + m] = g4;
            }
        }
    }
    __syncthreads();

    const ushort_t* rw = Rswz + (size_t)wv * 8192 + lane * 8;
    floatx4 rr[2][4];
    {
        float4 c0 = *(const float4*)(br + mb + quad * 4);
        float4 c1 = *(const float4*)(br + mb + 16 + quad * 4);
        #pragma unroll
        for (int nt = 0; nt < 4; ++nt) {
            rr[0][nt] = (floatx4){c0.x, c0.y, c0.z, c0.w};
            rr[1][nt] = (floatx4){c1.x, c1.y, c1.z, c1.w};
        }
    }
    #pragma unroll
    for (int s = 0; s < 8; ++s) {
        short8x a0 = *(const short8x*)(rw + s * 1024);
        short8x a1 = *(const short8x*)(rw + s * 1024 + 512);
        const int cb = l16 * STR + s * 32 + quad * 8;
        #pragma unroll
        for (int nt = 0; nt < 4; ++nt) {
            short8x bb = *(const short8x*)&st[cb + nt * 16 * STR];
            rr[0][nt] = __builtin_amdgcn_mfma_f32_16x16x32_bf16(a0, bb, rr[0][nt], 0, 0, 0);
            rr[1][nt] = __builtin_amdgcn_mfma_f32_16x16x32_bf16(a1, bb, rr[1][nt], 0, 0, 0);
        }
    }

    #pragma unroll
    for (int nt = 0; nt < 4; ++nt) {
        const int t = tb + nt * 16 + l16;
        if (t < s_out) continue;
        const size_t base = (size_t)(t - T0) * RES;
        #pragma unroll
        for (int mt = 0; mt < 2; ++mt) {
            const int m = mb + mt * 16 + quad * 4;
            floatx4 ad = rr[mt][nt];
            float4 ho = *(const float4*)(hfb + base + m);
            float4 hn = {ho.x + ad[0], ho.y + ad[1], ho.z + ad[2], ho.w + ad[3]};
            *(float4*)(hfb + base + m) = hn;
            ull pk = (ull)f2bf(hn.x) | ((ull)f2bf(hn.y) << 16)
                   | ((ull)f2bf(hn.z) << 32) | ((ull)f2bf(hn.w) << 48);
            *(ull*)(hB + base + m) = pk;
        }
    }
}

// All 30 skip matvecs in parallel: block (l,b), thread o
__global__ __launch_bounds__(512) void skip_kernel(
    const ushort_t* __restrict__ WsT, const float* __restrict__ bs,
    const float* __restrict__ gstore, float* __restrict__ skip)
{
    const int l = blockIdx.x, b = blockIdx.y, o = threadIdx.x;
    const ushort_t* w = WsT + (size_t)l * 131072;
    const float* g = gstore + (size_t)(l * BATCH + b) * RES;
    float a = bs[l * SKIPC + o];
    #pragma unroll 4
    for (int cin = 0; cin < RES; ++cin)
        a = fmaf(bf2f(w[cin * SKIPC + o]), g[cin], a);
    atomicAdd(&skip[b * SKIPC + o], a);
}

__global__ __launch_bounds__(256) void end1_kernel(
    const float* __restrict__ skip, const float* __restrict__ W1,
    const float* __restrict__ b1, float* __restrict__ e1ws)
{
    __shared__ float s[SKIPC];
    __shared__ float part[256];
    const int b = blockIdx.x, og = blockIdx.y, tid = threadIdx.x;
    s[tid]       = fmaxf(skip[b * SKIPC + tid], 0.f);
    s[tid + 256] = fmaxf(skip[b * SKIPC + tid + 256], 0.f);
    __syncthreads();
    const int o_l = tid >> 3, kp = tid & 7;
    const float* w = W1 + (size_t)(og * 32 + o_l) * SKIPC + kp * 64;
    const float* sp = s + kp * 64;
    float a = 0.f;
    #pragma unroll 8
    for (int j = 0; j < 64; ++j) a = fmaf(w[j], sp[j], a);
    part[tid] = a;
    __syncthreads();
    if (tid < 32) {
        float r = b1[og * 32 + tid];
        #pragma unroll
        for (int k = 0; k < 8; ++k) r += part[tid * 8 + k];
        e1ws[b * SKIPC + og * 32 + tid] = fmaxf(r, 0.f);
    }
}

__global__ __launch_bounds__(256) void end2_kernel(
    const float* __restrict__ e1ws, const float* __restrict__ W2,
    const float* __restrict__ b2, float* __restrict__ out)
{
    __shared__ float e[SKIPC];
    __shared__ float part[256];
    const int b = blockIdx.x, og = blockIdx.y, tid = threadIdx.x;
    e[tid]       = e1ws[b * SKIPC + tid];
    e[tid + 256] = e1ws[b * SKIPC + tid + 256];
    __syncthreads();
    const int o_l = tid >> 3, kp = tid & 7;
    const float* w = W2 + (size_t)(og * 32 + o_l) * SKIPC + kp * 64;
    const float* ep = e + kp * 64;
    float a = 0.f;
    #pragma unroll 8
    for (int j = 0; j < 64; ++j) a = fmaf(w[j], ep[j], a);
    part[tid] = a;
    __syncthreads();
    if (tid < 32) {
        float r = b2[og * 32 + tid];
        #pragma unroll
        for (int k = 0; k < 8; ++k) r += part[tid * 8 + k];
        out[b * NCLSC + og * 32 + tid] = r;
    }
}

extern "C" void kernel_launch(void* const* d_in, const int* in_sizes, int n_in,
                              void* d_out, int out_size, void* d_ws, size_t ws_size,
                              hipStream_t stream)
{
    const float* x   = (const float*)d_in[0];
    const float* Wst = (const float*)d_in[1];
    const float* bst = (const float*)d_in[2];
    const float* Wd  = (const float*)d_in[3];
    const float* bd  = (const float*)d_in[4];
    const float* Wr  = (const float*)d_in[5];
    const float* br  = (const float*)d_in[6];
    const float* Ws  = (const float*)d_in[7];
    const float* bs  = (const float*)d_in[8];
    const float* W1  = (const float*)d_in[9];
    const float* b1  = (const float*)d_in[10];
    const float* W2  = (const float*)d_in[11];
    const float* b2  = (const float*)d_in[12];
    float* out = (float*)d_out;

    char* w = (char*)d_ws;
    float* hf     = (float*)w;     w += (size_t)BATCH * TBUF * RES * 4;
    ushort_t* hb0 = (ushort_t*)w;  w += (size_t)BATCH * TBUF * RES * 2;
    ushort_t* hb1 = (ushort_t*)w;  w += (size_t)BATCH * TBUF * RES * 2;
    ushort_t* Asw = (ushort_t*)w;  w += (size_t)NLAYERS * RES * 512 * 2;
    ushort_t* Rsw = (ushort_t*)w;  w += (size_t)NLAYERS * RES * RES * 2;
    ushort_t* WsT = (ushort_t*)w;  w += (size_t)NLAYERS * RES * SKIPC * 2;
    float* gstore = (float*)w;     w += (size_t)NLAYERS * BATCH * RES * 4;
    float* skip   = (float*)w;     w += (size_t)BATCH * SKIPC * 4;
    float* e1ws   = (float*)w;     w += (size_t)BATCH * SKIPC * 4;

    prep_kernel<<<2880, 256, 0, stream>>>(Wd, Wr, Ws, Asw, Rsw, WsT);
    start_kernel<<<(BATCH * TBUF * RES) / 256, 256, 0, stream>>>(x, Wst, bst, hf, hb0);
    hipMemsetAsync(skip, 0, BATCH * SKIPC * 4, stream);

    int rem[NLAYERS + 1];
    rem[NLAYERS] = 0;
    for (int i = NLAYERS - 1; i >= 0; --i) rem[i] = rem[i + 1] + (1 << (i % 10));

    for (int i = 0; i < NLAYERS; ++i) {
        int dil = 1 << (i % 10);
        int s_out = 8191 - rem[i + 1];
        int L = 8192 - s_out;
        const ushort_t* hin = (i & 1) ? hb1 : hb0;
        ushort_t* hout = (i & 1) ? hb0 : hb1;
        if (dil <= 32) {
            int ntiles = (L + 63) / 64;
            layer64_kernel<<<dim3(ntiles, BATCH), 512, 0, stream>>>(
                hf, hin, hout,
                Asw + (size_t)i * RES * 512, bd + (size_t)i * RES,
                Rsw + (size_t)i * RES * RES, br + (size_t)i * RES,
                gstore + (size_t)i * BATCH * RES, dil, s_out);
        } else {
            int ntiles = (L + 31) / 32;
            layer32_kernel<<<dim3(ntiles, BATCH), 512, 0, stream>>>(
                hf, hin, hout,
                Asw + (size_t)i * RES * 512, bd + (size_t)i * RES,
                Rsw + (size_t)i * RES * RES, br + (size_t)i * RES,
                gstore + (size_t)i * BATCH * RES, dil, s_out);
        }
    }
    skip_kernel<<<dim3(NLAYERS, BATCH), 512, 0, stream>>>(WsT, bs, gstore, skip);
    end1_kernel<<<dim3(BATCH, 16), 256, 0, stream>>>(skip, W1, b1, e1ws);
    end2_kernel<<<dim3(BATCH, 8), 256, 0, stream>>>(e1ws, W2, b2, out);
}

// Round 8
// 629.307 us; speedup vs baseline: 2.6096x; 1.0109x over previous
//
#include <hip/hip_runtime.h>

#define BATCH 4
#define T 8192
#define RES 256
#define SKIPC 512
#define NCLSC 256
#define NLAYERS 30
#define T0 5120
#define TBUF 3072

typedef __attribute__((ext_vector_type(8))) short short8x;   // 8 bf16
typedef __attribute__((ext_vector_type(4))) float floatx4;   // MFMA C/D
typedef unsigned short ushort_t;
typedef unsigned long long ull;

__device__ __forceinline__ ushort_t f2bf(float f) {
    unsigned u = __float_as_uint(f);
    u += 0x7fffu + ((u >> 16) & 1u);
    return (ushort_t)(u >> 16);
}
__device__ __forceinline__ float bf2f(ushort_t h) {
    return __uint_as_float(((unsigned)h) << 16);
}
// tanh(d)*sigmoid(d) == (1-e^-d)/(1+e^-2d)
__device__ __forceinline__ float gatefn(float d) {
    float u = __expf(-fmaxf(d, -80.f));
    return (1.f - u) * __builtin_amdgcn_rcpf(fmaf(u, u, 1.f));
}
// XOR-swizzled LDS tile: 128 rows x 32 chunks x 16B = 64 KB, conflict-free
__device__ __forceinline__ int sw(int row, int chunk) {
    return row * 256 + ((chunk ^ (row & 7)) << 3);           // short index
}

// ---------------------------------------------------------------------------
// prep: coalesced weight swizzle into MFMA A-fragment order (as R6, validated).
// ---------------------------------------------------------------------------
__global__ __launch_bounds__(256) void prep_kernel(
    const float* __restrict__ Wd, const float* __restrict__ Wr,
    const float* __restrict__ Ws,
    ushort_t* __restrict__ Asw, ushort_t* __restrict__ Rsw,
    ushort_t* __restrict__ WsT)
{
    __shared__ ushort_t lt[64][72];
    const int bid = blockIdx.x, tid = threadIdx.x;
    const int wv = tid >> 6, lane = tid & 63;

    if (bid < 960) {              // Wd
        const int task = bid * 4 + wv;
        const int l = task >> 7, p = task & 127;
        const int half = lane >> 5, c = lane & 31;
        const int row = p * 2 + half;
        const float* src = Wd + ((size_t)(l * 256 + row)) * 512 + c * 16;
        float4 v0 = *(const float4*)(src);
        float4 v1 = *(const float4*)(src + 4);
        float4 v2 = *(const float4*)(src + 8);
        float4 v3 = *(const float4*)(src + 12);
        short8x p0, p1;
        p0[0]=(short)f2bf(v0.x); p0[1]=(short)f2bf(v0.z); p0[2]=(short)f2bf(v1.x); p0[3]=(short)f2bf(v1.z);
        p0[4]=(short)f2bf(v2.x); p0[5]=(short)f2bf(v2.z); p0[6]=(short)f2bf(v3.x); p0[7]=(short)f2bf(v3.z);
        p1[0]=(short)f2bf(v0.y); p1[1]=(short)f2bf(v0.w); p1[2]=(short)f2bf(v1.y); p1[3]=(short)f2bf(v1.w);
        p1[4]=(short)f2bf(v2.y); p1[5]=(short)f2bf(v2.w); p1[6]=(short)f2bf(v3.y); p1[7]=(short)f2bf(v3.w);
        const int wr = row >> 5, f = (row >> 4) & 1, l16 = row & 15;
        const int s0 = c >> 2, q = c & 3;
        size_t base = (size_t)l * 131072
                    + (size_t)(((wr * 16 + s0) * 2 + f) * 64 + q * 16 + l16) * 8;
        *(short8x*)(Asw + base) = p0;
        *(short8x*)(Asw + base + 8192) = p1;
        return;
    }
    if (bid < 1920) {             // Wr
        const int task = (bid - 960) * 4 + wv;
        const int l = task >> 7, p = task & 127;
        const int half = lane >> 5, c = lane & 31;
        const int row = p * 2 + half;
        const float* src = Wr + ((size_t)(l * 256 + row)) * 256 + c * 8;
        float4 v0 = *(const float4*)(src);
        float4 v1 = *(const float4*)(src + 4);
        short8x pk;
        pk[0]=(short)f2bf(v0.x); pk[1]=(short)f2bf(v0.y); pk[2]=(short)f2bf(v0.z); pk[3]=(short)f2bf(v0.w);
        pk[4]=(short)f2bf(v1.x); pk[5]=(short)f2bf(v1.y); pk[6]=(short)f2bf(v1.z); pk[7]=(short)f2bf(v1.w);
        const int wr = row >> 5, f = (row >> 4) & 1, l16 = row & 15;
        const int s = c >> 2, q = c & 3;
        size_t base = (size_t)l * 65536
                    + (size_t)(((wr * 8 + s) * 2 + f) * 64 + q * 16 + l16) * 8;
        *(short8x*)(Rsw + base) = pk;
        return;
    }
    {                             // Ws transpose
        const int t = bid - 1920;
        const int l = t >> 5, r = t & 31, ot = r >> 2, ct = r & 3;
        #pragma unroll 4
        for (int it = 0; it < 16; ++it) {
            int o_l = it * 4 + (tid >> 6), cin_l = tid & 63;
            lt[cin_l][o_l] = f2bf(Ws[((size_t)(l * 512 + ot * 64 + o_l)) * 256 + ct * 64 + cin_l]);
        }
        __syncthreads();
        #pragma unroll 4
        for (int it = 0; it < 16; ++it) {
            int cin_l = it * 4 + (tid >> 6), o_l = tid & 63;
            WsT[(size_t)l * 131072 + (size_t)(ct * 64 + cin_l) * 512 + ot * 64 + o_l] = lt[cin_l][o_l];
        }
    }
}

// h0[b][t][c] fp32+bf16; also zero skip.
__global__ __launch_bounds__(256) void start_kernel(
    const float* __restrict__ x, const float* __restrict__ Wst,
    const float* __restrict__ bst, float* __restrict__ hf, ushort_t* __restrict__ hb,
    float* __restrict__ skip)
{
    int id = blockIdx.x * 256 + threadIdx.x;
    if (id < BATCH * SKIPC) skip[id] = 0.f;
    int c = id & 255;
    int ti = (id >> 8) % TBUF;
    int b  = (id >> 8) / TBUF;
    int t = T0 + ti;
    float v = Wst[2 * c] * x[b * T + t - 1] + Wst[2 * c + 1] * x[b * T + t] + bst[c];
    hf[id] = v;
    hb[id] = f2bf(v);
}

// ---------------------------------------------------------------------------
// fused6: 6 layers (dil 1..32) in one dispatch. Block = 256ch x (64 out + 64
// halo) cols. Intermediate h in LDS (bf16) + registers (fp32 for out cols).
// Halo hreg comes from the READ-ONLY bf16 ping buffer (hf halo would race
// tile+1's epilogue hf writes). Garbage drift = Sum(dil) = 63 < 64.
// ---------------------------------------------------------------------------
__global__ __launch_bounds__(512, 2) void fused6_kernel(
    float* __restrict__ hf, const ushort_t* __restrict__ hbA, ushort_t* __restrict__ hbB,
    const ushort_t* __restrict__ Asw6, const float* __restrict__ bd6,
    const ushort_t* __restrict__ Rsw6, const float* __restrict__ br6,
    float* __restrict__ gstore6, int s_out)
{
    __shared__ __align__(16) ushort_t st[32768];   // 64 KB swizzled [128][32][8]

    const int tid = threadIdx.x;
    const int wv = tid >> 6, lane = tid & 63;
    const int quad = lane >> 4, l16 = lane & 15;
    const int tile = blockIdx.x, b = blockIdx.y;
    const int tb = 8192 - 64 * (tile + 1);
    const int mb = wv * 32;

    float* __restrict__ hfb = hf + (size_t)b * TBUF * RES;
    const ushort_t* __restrict__ hA = hbA + (size_t)b * TBUF * RES;
    ushort_t* __restrict__ hB = hbB + (size_t)b * TBUF * RES;

    // stage rows 0..127 <-> t = tb-64+row
    #pragma unroll
    for (int p = 0; p < 8; ++p) {
        int idx = p * 512 + tid;
        int row = idx >> 5, c = idx & 31;
        int tt = tb - 64 + row - T0;
        tt = tt < 0 ? 0 : tt;
        *(float4*)&st[sw(row, c)] = *(const float4*)(hA + (size_t)tt * RES + c * 8);
    }
    // residual fragments: out cols (nt>=4) fp32 from hf (t-T0 indexing!);
    // halo cols (nt<4) from bf16 hA (race-free; never stored anyway).
    floatx4 hreg[2][8];
    #pragma unroll
    for (int nt = 0; nt < 8; ++nt) {
        int ti = tb - 64 + nt * 16 + l16 - T0;
        ti = ti < 0 ? 0 : ti;
        if (nt < 4) {
            const ushort_t* hp = hA + (size_t)ti * RES + mb + quad * 4;
            ull v0 = *(const ull*)(hp);
            ull v1 = *(const ull*)(hp + 16);
            floatx4 f0, f1;
            #pragma unroll
            for (int r = 0; r < 4; ++r) {
                f0[r] = bf2f((ushort_t)(v0 >> (16 * r)));
                f1[r] = bf2f((ushort_t)(v1 >> (16 * r)));
            }
            hreg[0][nt] = f0;
            hreg[1][nt] = f1;
        } else {
            const float* hp = hfb + (size_t)ti * RES + mb + quad * 4;
            hreg[0][nt] = *(const floatx4*)(hp);
            hreg[1][nt] = *(const floatx4*)(hp + 16);
        }
    }
    __syncthreads();

    #pragma unroll 1
    for (int j = 0; j < 6; ++j) {
        const int d = 1 << j;
        const ushort_t* aw = Asw6 + (size_t)j * 131072 + wv * 16384 + lane * 8;

        floatx4 acc[2][8];
        {
            const float* bp = bd6 + j * 256 + mb + quad * 4;
            floatx4 c0 = *(const floatx4*)bp;
            floatx4 c1 = *(const floatx4*)(bp + 16);
            #pragma unroll
            for (int nt = 0; nt < 8; ++nt) { acc[0][nt] = c0; acc[1][nt] = c1; }
        }
        int r0[8];
        #pragma unroll
        for (int nt = 0; nt < 8; ++nt) {
            int r = nt * 16 + l16 - d;
            r0[nt] = r < 0 ? 0 : r;
        }
        #pragma unroll
        for (int s = 0; s < 16; ++s) {
            short8x a0 = *(const short8x*)(aw + s * 1024);
            short8x a1 = *(const short8x*)(aw + s * 1024 + 512);
            const int ch = (s & 7) * 4 + quad;
            #pragma unroll
            for (int nt = 0; nt < 8; ++nt) {
                int rt = (s < 8) ? r0[nt] : (nt * 16 + l16);
                short8x bb = *(const short8x*)&st[sw(rt, ch)];
                acc[0][nt] = __builtin_amdgcn_mfma_f32_16x16x32_bf16(a0, bb, acc[0][nt], 0, 0, 0);
                acc[1][nt] = __builtin_amdgcn_mfma_f32_16x16x32_bf16(a1, bb, acc[1][nt], 0, 0, 0);
            }
        }
        __syncthreads();                       // conv reads done -> overwrite with gated

        #pragma unroll
        for (int mt = 0; mt < 2; ++mt) {
            #pragma unroll
            for (int nt = 0; nt < 8; ++nt) {
                floatx4 a = acc[mt][nt];
                float gf[4];
                ull pk = 0;
                #pragma unroll
                for (int r = 0; r < 4; ++r) {
                    gf[r] = gatefn(a[r]);
                    pk |= ((ull)f2bf(gf[r])) << (16 * r);
                }
                const int n = nt * 16 + l16;
                const int m = mb + mt * 16 + quad * 4;
                *(ull*)&st[n * 256 + (((m >> 3) ^ (n & 7)) << 3) + (m & 7)] = pk;
                if (tile == 0 && n == 127) {
                    float4 g4 = {gf[0], gf[1], gf[2], gf[3]};
                    *(float4*)&gstore6[(size_t)j * BATCH * RES + b * RES + m] = g4;
                }
            }
        }
        __syncthreads();                       // gated visible

        const ushort_t* rw = Rsw6 + (size_t)j * 65536 + wv * 8192 + lane * 8;
        floatx4 racc[2][8];
        {
            const float* bp = br6 + j * 256 + mb + quad * 4;
            floatx4 c0 = *(const floatx4*)bp;
            floatx4 c1 = *(const floatx4*)(bp + 16);
            #pragma unroll
            for (int nt = 0; nt < 8; ++nt) { racc[0][nt] = c0; racc[1][nt] = c1; }
        }
        #pragma unroll
        for (int s = 0; s < 8; ++s) {
            short8x a0 = *(const short8x*)(rw + s * 1024);
            short8x a1 = *(const short8x*)(rw + s * 1024 + 512);
            const int ch = s * 4 + quad;
            #pragma unroll
            for (int nt = 0; nt < 8; ++nt) {
                short8x bb = *(const short8x*)&st[sw(nt * 16 + l16, ch)];
                racc[0][nt] = __builtin_amdgcn_mfma_f32_16x16x32_bf16(a0, bb, racc[0][nt], 0, 0, 0);
                racc[1][nt] = __builtin_amdgcn_mfma_f32_16x16x32_bf16(a1, bb, racc[1][nt], 0, 0, 0);
            }
        }
        __syncthreads();                       // gated reads done -> overwrite with h

        #pragma unroll
        for (int mt = 0; mt < 2; ++mt) {
            #pragma unroll
            for (int nt = 0; nt < 8; ++nt) {
                hreg[mt][nt] += racc[mt][nt];
                floatx4 h = hreg[mt][nt];
                ull pk = (ull)f2bf(h[0]) | ((ull)f2bf(h[1]) << 16)
                       | ((ull)f2bf(h[2]) << 32) | ((ull)f2bf(h[3]) << 48);
                const int n = nt * 16 + l16;
                const int m = mb + mt * 16 + quad * 4;
                *(ull*)&st[n * 256 + (((m >> 3) ^ (n & 7)) << 3) + (m & 7)] = pk;
            }
        }
        __syncthreads();                       // h visible for next layer's conv
    }

    // epilogue: store cols n>=64 (t = tb-64+n) passing the s_out guard
    #pragma unroll
    for (int nt = 4; nt < 8; ++nt) {
        const int t = tb - 64 + nt * 16 + l16;
        if (t < s_out) continue;
        const size_t base = (size_t)(t - T0) * RES;
        #pragma unroll
        for (int mt = 0; mt < 2; ++mt) {
            const int m = mb + mt * 16 + quad * 4;
            floatx4 h = hreg[mt][nt];
            *(floatx4*)(hfb + base + m) = h;
            ull pk = (ull)f2bf(h[0]) | ((ull)f2bf(h[1]) << 16)
                   | ((ull)f2bf(h[2]) << 32) | ((ull)f2bf(h[3]) << 48);
            *(ull*)(hB + base + m) = pk;
        }
    }
}

// ---------------------------------------------------------------------------
// layer1: one big-dil layer, NT=64 (rows 0..63 tap t-dil, 64..127 tap t).
// ---------------------------------------------------------------------------
__global__ __launch_bounds__(512, 2) void layer1_kernel(
    float* __restrict__ hf, const ushort_t* __restrict__ hbA, ushort_t* __restrict__ hbB,
    const ushort_t* __restrict__ AswL, const float* __restrict__ bdL,
    const ushort_t* __restrict__ RswL, const float* __restrict__ brL,
    float* __restrict__ gsL, int dil, int s_out)
{
    __shared__ __align__(16) ushort_t st[32768];

    const int tid = threadIdx.x;
    const int wv = tid >> 6, lane = tid & 63;
    const int quad = lane >> 4, l16 = lane & 15;
    const int tile = blockIdx.x, b = blockIdx.y;
    const int tb = 8192 - 64 * (tile + 1);
    const int mb = wv * 32;

    float* __restrict__ hfb = hf + (size_t)b * TBUF * RES;
    const ushort_t* __restrict__ hA = hbA + (size_t)b * TBUF * RES;
    ushort_t* __restrict__ hB = hbB + (size_t)b * TBUF * RES;

    #pragma unroll
    for (int p = 0; p < 8; ++p) {
        int idx = p * 512 + tid;
        int row = idx >> 5, c = idx & 31;
        int tt = (row < 64) ? (tb + row - dil) : (tb + row - 64);
        tt -= T0;
        tt = tt < 0 ? 0 : tt;
        *(float4*)&st[sw(row, c)] = *(const float4*)(hA + (size_t)tt * RES + c * 8);
    }
    __syncthreads();

    const ushort_t* aw = AswL + wv * 16384 + lane * 8;
    floatx4 acc[2][4];
    {
        const float* bp = bdL + mb + quad * 4;
        floatx4 c0 = *(const floatx4*)bp;
        floatx4 c1 = *(const floatx4*)(bp + 16);
        #pragma unroll
        for (int nt = 0; nt < 4; ++nt) { acc[0][nt] = c0; acc[1][nt] = c1; }
    }
    #pragma unroll
    for (int s = 0; s < 16; ++s) {
        short8x a0 = *(const short8x*)(aw + s * 1024);
        short8x a1 = *(const short8x*)(aw + s * 1024 + 512);
        const int ch = (s & 7) * 4 + quad;
        const int rbase = (s < 8) ? 0 : 64;
        #pragma unroll
        for (int nt = 0; nt < 4; ++nt) {
            short8x bb = *(const short8x*)&st[sw(rbase + nt * 16 + l16, ch)];
            acc[0][nt] = __builtin_amdgcn_mfma_f32_16x16x32_bf16(a0, bb, acc[0][nt], 0, 0, 0);
            acc[1][nt] = __builtin_amdgcn_mfma_f32_16x16x32_bf16(a1, bb, acc[1][nt], 0, 0, 0);
        }
    }
    __syncthreads();

    #pragma unroll
    for (int mt = 0; mt < 2; ++mt) {
        #pragma unroll
        for (int nt = 0; nt < 4; ++nt) {
            floatx4 a = acc[mt][nt];
            float gf[4];
            ull pk = 0;
            #pragma unroll
            for (int r = 0; r < 4; ++r) {
                gf[r] = gatefn(a[r]);
                pk |= ((ull)f2bf(gf[r])) << (16 * r);
            }
            const int n = nt * 16 + l16;
            const int m = mb + mt * 16 + quad * 4;
            *(ull*)&st[n * 256 + (((m >> 3) ^ (n & 7)) << 3) + (m & 7)] = pk;
            if (tile == 0 && n == 63) {
                float4 g4 = {gf[0], gf[1], gf[2], gf[3]};
                *(float4*)&gsL[b * RES + m] = g4;
            }
        }
    }
    __syncthreads();

    const ushort_t* rw = RswL + wv * 8192 + lane * 8;
    floatx4 rr[2][4];
    {
        const float* bp = brL + mb + quad * 4;
        floatx4 c0 = *(const floatx4*)bp;
        floatx4 c1 = *(const floatx4*)(bp + 16);
        #pragma unroll
        for (int nt = 0; nt < 4; ++nt) { rr[0][nt] = c0; rr[1][nt] = c1; }
    }
    #pragma unroll
    for (int s = 0; s < 8; ++s) {
        short8x a0 = *(const short8x*)(rw + s * 1024);
        short8x a1 = *(const short8x*)(rw + s * 1024 + 512);
        const int ch = s * 4 + quad;
        #pragma unroll
        for (int nt = 0; nt < 4; ++nt) {
            short8x bb = *(const short8x*)&st[sw(nt * 16 + l16, ch)];
            rr[0][nt] = __builtin_amdgcn_mfma_f32_16x16x32_bf16(a0, bb, rr[0][nt], 0, 0, 0);
            rr[1][nt] = __builtin_amdgcn_mfma_f32_16x16x32_bf16(a1, bb, rr[1][nt], 0, 0, 0);
        }
    }

    #pragma unroll
    for (int nt = 0; nt < 4; ++nt) {
        const int t = tb + nt * 16 + l16;
        if (t < s_out) continue;
        const size_t base = (size_t)(t - T0) * RES;
        #pragma unroll
        for (int mt = 0; mt < 2; ++mt) {
            const int m = mb + mt * 16 + quad * 4;
            floatx4 ad = rr[mt][nt];
            float4 ho = *(const float4*)(hfb + base + m);
            float4 hn = {ho.x + ad[0], ho.y + ad[1], ho.z + ad[2], ho.w + ad[3]};
            *(float4*)(hfb + base + m) = hn;
            ull pk = (ull)f2bf(hn.x) | ((ull)f2bf(hn.y) << 16)
                   | ((ull)f2bf(hn.z) << 32) | ((ull)f2bf(hn.w) << 48);
            *(ull*)(hB + base + m) = pk;
        }
    }
}

// All 30 skip matvecs: block (l,b), thread o
__global__ __launch_bounds__(512) void skip_kernel(
    const ushort_t* __restrict__ WsT, const float* __restrict__ bs,
    const float* __restrict__ gstore, float* __restrict__ skip)
{
    const int l = blockIdx.x, b = blockIdx.y, o = threadIdx.x;
    const ushort_t* w = WsT + (size_t)l * 131072;
    const float* g = gstore + (size_t)(l * BATCH + b) * RES;
    float a = bs[l * SKIPC + o];
    #pragma unroll 4
    for (int cin = 0; cin < RES; ++cin)
        a = fmaf(bf2f(w[cin * SKIPC + o]), g[cin], a);
    atomicAdd(&skip[b * SKIPC + o], a);
}

__global__ __launch_bounds__(256) void end1_kernel(
    const float* __restrict__ skip, const float* __restrict__ W1,
    const float* __restrict__ b1, float* __restrict__ e1ws)
{
    __shared__ float s[SKIPC];
    __shared__ float part[256];
    const int b = blockIdx.x, og = blockIdx.y, tid = threadIdx.x;
    s[tid]       = fmaxf(skip[b * SKIPC + tid], 0.f);
    s[tid + 256] = fmaxf(skip[b * SKIPC + tid + 256], 0.f);
    __syncthreads();
    const int o_l = tid >> 3, kp = tid & 7;
    const float* w = W1 + (size_t)(og * 32 + o_l) * SKIPC + kp * 64;
    const float* sp = s + kp * 64;
    float a = 0.f;
    #pragma unroll 8
    for (int j = 0; j < 64; ++j) a = fmaf(w[j], sp[j], a);
    part[tid] = a;
    __syncthreads();
    if (tid < 32) {
        float r = b1[og * 32 + tid];
        #pragma unroll
        for (int k = 0; k < 8; ++k) r += part[tid * 8 + k];
        e1ws[b * SKIPC + og * 32 + tid] = fmaxf(r, 0.f);
    }
}

__global__ __launch_bounds__(256) void end2_kernel(
    const float* __restrict__ e1ws, const float* __restrict__ W2,
    const float* __restrict__ b2, float* __restrict__ out)
{
    __shared__ float e[SKIPC];
    __shared__ float part[256];
    const int b = blockIdx.x, og = blockIdx.y, tid = threadIdx.x;
    e[tid]       = e1ws[b * SKIPC + tid];
    e[tid + 256] = e1ws[b * SKIPC + tid + 256];
    __syncthreads();
    const int o_l = tid >> 3, kp = tid & 7;
    const float* w = W2 + (size_t)(og * 32 + o_l) * SKIPC + kp * 64;
    const float* ep = e + kp * 64;
    float a = 0.f;
    #pragma unroll 8
    for (int j = 0; j < 64; ++j) a = fmaf(w[j], ep[j], a);
    part[tid] = a;
    __syncthreads();
    if (tid < 32) {
        float r = b2[og * 32 + tid];
        #pragma unroll
        for (int k = 0; k < 8; ++k) r += part[tid * 8 + k];
        out[b * NCLSC + og * 32 + tid] = r;
    }
}

extern "C" void kernel_launch(void* const* d_in, const int* in_sizes, int n_in,
                              void* d_out, int out_size, void* d_ws, size_t ws_size,
                              hipStream_t stream)
{
    const float* x   = (const float*)d_in[0];
    const float* Wst = (const float*)d_in[1];
    const float* bst = (const float*)d_in[2];
    const float* Wd  = (const float*)d_in[3];
    const float* bd  = (const float*)d_in[4];
    const float* Wr  = (const float*)d_in[5];
    const float* br  = (const float*)d_in[6];
    const float* Ws  = (const float*)d_in[7];
    const float* bs  = (const float*)d_in[8];
    const float* W1  = (const float*)d_in[9];
    const float* b1  = (const float*)d_in[10];
    const float* W2  = (const float*)d_in[11];
    const float* b2  = (const float*)d_in[12];
    float* out = (float*)d_out;

    char* w = (char*)d_ws;
    float* hf     = (float*)w;     w += (size_t)BATCH * TBUF * RES * 4;
    ushort_t* hb0 = (ushort_t*)w;  w += (size_t)BATCH * TBUF * RES * 2;
    ushort_t* hb1 = (ushort_t*)w;  w += (size_t)BATCH * TBUF * RES * 2;
    ushort_t* Asw = (ushort_t*)w;  w += (size_t)NLAYERS * RES * 512 * 2;
    ushort_t* Rsw = (ushort_t*)w;  w += (size_t)NLAYERS * RES * RES * 2;
    ushort_t* WsT = (ushort_t*)w;  w += (size_t)NLAYERS * RES * SKIPC * 2;
    float* gstore = (float*)w;     w += (size_t)NLAYERS * BATCH * RES * 4;
    float* skip   = (float*)w;     w += (size_t)BATCH * SKIPC * 4;
    float* e1ws   = (float*)w;     w += (size_t)BATCH * SKIPC * 4;

    prep_kernel<<<2880, 256, 0, stream>>>(Wd, Wr, Ws, Asw, Rsw, WsT);
    start_kernel<<<(BATCH * TBUF * RES) / 256, 256, 0, stream>>>(x, Wst, bst, hf, hb0, skip);

    int rem[NLAYERS + 1];
    rem[NLAYERS] = 0;
    for (int i = NLAYERS - 1; i >= 0; --i) rem[i] = rem[i + 1] + (1 << (i % 10));

    ushort_t* hin = hb0;
    ushort_t* hout = hb1;
    for (int s3 = 0; s3 < 3; ++s3) {
        const int lb = s3 * 10;
        {   // layers lb..lb+5 fused (dil 1..32)
            int so = 8191 - rem[lb + 6];
            int K = (rem[lb + 6] + 1 + 63) / 64;
            fused6_kernel<<<dim3(K, BATCH), 512, 0, stream>>>(
                hf, hin, hout,
                Asw + (size_t)lb * 131072, bd + lb * 256,
                Rsw + (size_t)lb * 65536, br + lb * 256,
                gstore + (size_t)lb * BATCH * RES, so);
            ushort_t* tmp = hin; hin = hout; hout = tmp;
        }
        for (int i = lb + 6; i < lb + 10; ++i) {   // dil 64..512
            int dil = 1 << (i % 10);
            int so = 8191 - rem[i + 1];
            int K = (rem[i + 1] + 1 + 63) / 64;
            layer1_kernel<<<dim3(K, BATCH), 512, 0, stream>>>(
                hf, hin, hout,
                Asw + (size_t)i * 131072, bd + i * 256,
                Rsw + (size_t)i * 65536, br + i * 256,
                gstore + (size_t)i * BATCH * RES, dil, so);
            ushort_t* tmp = hin; hin = hout; hout = tmp;
        }
    }
    skip_kernel<<<dim3(NLAYERS, BATCH), 512, 0, stream>>>(WsT, bs, gstore, skip);
    end1_kernel<<<dim3(BATCH, 16), 256, 0, stream>>>(skip, W1, b1, e1ws);
    end2_kernel<<<dim3(BATCH, 8), 256, 0, stream>>>(e1ws, W2, b2, out);
}